// Round 4
// baseline (25.525 us; speedup 1.0000x reference)
//
#include <hip/hip_runtime.h>
#include <hip/hip_bf16.h>

#define NNODE 25
#define HID   128
#define GB    32
#define BLOCK 512
#define KTOT  256
#define SPAD  264
#define XTW   36     // Xt row stride (floats): 144B = 4-bank offset/row -> 2-way (free)

// ws layout (bytes)
#define WS_WT   0        // u16 [128][256]  W2cat^T bf16
#define WS_MTB  65536    // u16 [32][32]    M bf16, zero-padded
#define WS_CVEC 67584    // f32 [32]        (1/25) * colsum(M), zero-padded
#define WS_W1B  67712    // u16 [128][8]    {W1l[0..2][c], W1r[0..2][c], 0, 0}

typedef __attribute__((ext_vector_type(8))) short short8;
typedef __attribute__((ext_vector_type(4))) float f32x4;
typedef __attribute__((ext_vector_type(2))) float f32x2;

__device__ inline unsigned short f2bf(float f) {
  __hip_bfloat16 h = __float2bfloat16(f);
  unsigned short u; __builtin_memcpy(&u, &h, 2); return u;
}

// Xbf cell: node n, batch g (0..31), 8 bf16/cell; g XOR-swizzled in low 4 bits
#define XB(n, g) (((n)*GB + ((g) ^ ((n) & 15))) * 8)

__global__ __launch_bounds__(256) void prep(
    const float* __restrict__ W2l, const float* __restrict__ W2r,
    const float* __restrict__ W1l, const float* __restrict__ W1r,
    const int*   __restrict__ ei,  unsigned char* __restrict__ ws)
{
  const int blk = blockIdx.x, tid = threadIdx.x;
  if (blk < 128) {             // Wt[o][k] = bf16(W2cat[k][o])
    unsigned short* Wt = (unsigned short*)(ws + WS_WT);
    int i = blk*256 + tid;
    int o = i >> 8, k = i & 255;
    float v = (k < HID) ? W2l[k*HID + o] : W2r[(k-HID)*HID + o];
    Wt[o*KTOT + k] = f2bf(v);
    return;
  }
  // block 128: M, cvec, W1b
  __shared__ float Mm[NNODE*NNODE];
  __shared__ float cnt[NNODE];
  for (int i = tid; i < NNODE*NNODE; i += 256) Mm[i] = 0.f;
  if (tid < NNODE) cnt[tid] = 0.f;
  __syncthreads();
  if (tid < 64) {
    int s = ei[tid], d = ei[64 + tid];
    atomicAdd(&Mm[d*NNODE + s], 1.f);
    atomicAdd(&cnt[d], 1.f);
  }
  __syncthreads();
  for (int i = tid; i < NNODE*NNODE; i += 256) {
    int n = i / NNODE;
    Mm[i] *= 1.f / fmaxf(cnt[n], 1.f);
  }
  __syncthreads();
  unsigned short* Mtb = (unsigned short*)(ws + WS_MTB);
  for (int i = tid; i < 1024; i += 256) {
    int n = i >> 5, m = i & 31;
    float v = (n < NNODE && m < NNODE) ? Mm[n*NNODE + m] : 0.f;
    Mtb[i] = f2bf(v);
  }
  if (tid < 32) {
    float a = 0.f;
    if (tid < NNODE)
      for (int n = 0; n < NNODE; ++n) a += Mm[n*NNODE + tid];
    ((float*)(ws + WS_CVEC))[tid] = a * (1.f/NNODE);
  }
  unsigned short* W1b = (unsigned short*)(ws + WS_W1B);
  for (int i = tid; i < 1024; i += 256) {
    int c = i >> 3, j = i & 7;
    float v = (j < 3) ? W1l[j*HID + c] : (j < 6) ? W1r[(j-3)*HID + c] : 0.f;
    W1b[i] = f2bf(v);
  }
}

__global__ __launch_bounds__(BLOCK, 4) void gnn_fused(
    const float* __restrict__ x,        // [B][25][3]
    const float* __restrict__ b1,       // [128]
    const float* __restrict__ b2,       // [128]
    const unsigned char* __restrict__ ws,
    float* __restrict__ out)            // [B][128]
{
  __shared__ __align__(16) unsigned short Mtb[32][32];
  __shared__ float cvecs[32];
  __shared__ __align__(16) float Xt[3][GB][XTW];           // x[d][g][m], m 25..31 = 0
  __shared__ __align__(16) unsigned short Xbf[NNODE*GB*8]; // {agg0..2, x0..2, 0, 0}
  __shared__ __align__(16) unsigned short Sbf[GB][SPAD];   // [s1(128) | s2(128)]

  const int tid  = threadIdx.x;
  const int b0   = blockIdx.x * GB;
  const int wave = tid >> 6;
  const int lane = tid & 63;
  const int r    = lane & 15;
  const int kg   = lane >> 4;
  const f32x4 zz = {0.f, 0.f, 0.f, 0.f};

  // ---- phase A: load shared tables + x ----
  ((unsigned int*)Mtb)[tid] = ((const unsigned int*)(ws + WS_MTB))[tid]; // 512 dwords
  if (tid < 32) cvecs[tid] = ((const float*)(ws + WS_CVEC))[tid];
  for (int i = tid; i < GB*NNODE*3; i += BLOCK) {          // 2400 floats, coalesced
    int g = i / 75, rm = i - g*75;
    int n = rm / 3, d = rm - n*3;
    float v = x[(size_t)b0*75 + i];
    Xt[d][g][n] = v;
    Xbf[XB(n, g) + 3 + d] = f2bf(v);
  }
  if (tid < 672) {                                         // Xt[d][g][25..31] = 0
    int d = tid / 224, rm = tid % 224;
    Xt[d][rm/7][25 + rm%7] = 0.f;
  }
  for (int p = tid; p < NNODE*GB; p += BLOCK) {            // Xbf slots 6,7 = 0
    int n = p >> 5, g = p & 31;
    *(unsigned int*)&Xbf[XB(n, g) + 6] = 0u;
  }
  __syncthreads();

  // ---- phase B: agg via MFMA; waves 0..5 -> (d, g-tile) ----
  if (wave < 6) {
    const int d = wave >> 1, gt = wave & 1;
    short8 mb0 = *(const short8*)&Mtb[r][kg*8];        // B[k=m][col=n], n=r
    short8 mb1 = *(const short8*)&Mtb[16 + r][kg*8];   // n=16+r (rows >=25 are zero)
    f32x4 x0 = *(const f32x4*)&Xt[d][gt*16 + r][kg*8];
    f32x4 x1 = *(const f32x4*)&Xt[d][gt*16 + r][kg*8 + 4];
    short8 af;
    af[0]=(short)f2bf(x0[0]); af[1]=(short)f2bf(x0[1]);
    af[2]=(short)f2bf(x0[2]); af[3]=(short)f2bf(x0[3]);
    af[4]=(short)f2bf(x1[0]); af[5]=(short)f2bf(x1[1]);
    af[6]=(short)f2bf(x1[2]); af[7]=(short)f2bf(x1[3]);
    f32x4 g0 = __builtin_amdgcn_mfma_f32_16x16x32_bf16(af, mb0, zz, 0, 0, 0);
    f32x4 g1 = __builtin_amdgcn_mfma_f32_16x16x32_bf16(af, mb1, zz, 0, 0, 0);
    #pragma unroll
    for (int q = 0; q < 4; ++q) {
      int g = gt*16 + kg*4 + q;          // C row = batch (within block)
      Xbf[XB(r, g) + d] = f2bf(g0[q]);   // C col = node n = r
      if (r < 9) Xbf[XB(16 + r, g) + d] = f2bf(g1[q]);
    }
  }
  __syncthreads();

  // ---- phase C: stage 1 via MFMA (effective K=8), n-reduction packed f32 ----
  {
    const int gt = wave >> 2;
    const int c0 = (wave & 3) * 32;
    const int cA = c0 + r, cB = c0 + 16 + r;
    const unsigned short* W1b = (const unsigned short*)(ws + WS_W1B);
    short8 bfA = {0,0,0,0,0,0,0,0}, bfB = {0,0,0,0,0,0,0,0};
    if (kg == 0) {
      bfA = *(const short8*)&W1b[cA * 8];
      bfB = *(const short8*)&W1b[cB * 8];
    }
    f32x2 bias; bias.x = b1[cA]; bias.y = b1[cB];
    f32x2 s1[4] = {}, s2[4] = {};
    for (int n = 0; n < NNODE; ++n) {
      short8 a = *(const short8*)&Xbf[XB(n, gt*16 + r)];
      f32x4 h0 = __builtin_amdgcn_mfma_f32_16x16x32_bf16(a, bfA, zz, 0, 0, 0);
      f32x4 h1 = __builtin_amdgcn_mfma_f32_16x16x32_bf16(a, bfB, zz, 0, 0, 0);
      const float cv = cvecs[n];
      const f32x2 cvv = {cv, cv};
      #pragma unroll
      for (int q = 0; q < 4; ++q) {
        f32x2 v; v.x = h0[q]; v.y = h1[q];
        v += bias;
        v.x = fmaxf(v.x, 0.f); v.y = fmaxf(v.y, 0.f);
        s1[q] += cvv * v;
        s2[q] += v;
      }
    }
    #pragma unroll
    for (int q = 0; q < 4; ++q) {
      int g = gt*16 + kg*4 + q;
      Sbf[g][cA]       = f2bf(s1[q].x);
      Sbf[g][cB]       = f2bf(s1[q].y);
      Sbf[g][HID + cA] = f2bf(s2[q].x * (1.f/NNODE));
      Sbf[g][HID + cB] = f2bf(s2[q].y * (1.f/NNODE));
    }
  }
  __syncthreads();

  // ---- phase D: stage 2: out[32x128] = S[32x256] @ W2cat via MFMA ----
  {
    const int gt = wave >> 2;
    const int n0 = (wave & 3) * 32;
    const unsigned short* Wt = (const unsigned short*)(ws + WS_WT);
    const unsigned short* WtA = Wt + (size_t)(n0 + r)      * KTOT;
    const unsigned short* WtB = Wt + (size_t)(n0 + 16 + r) * KTOT;
    f32x4 acc0 = zz, acc1 = zz;
    #pragma unroll 2
    for (int kt = 0; kt < 8; ++kt) {
      const int kb = kt*32 + kg*8;
      short8 a  = *(const short8*)&Sbf[gt*16 + r][kb];
      short8 bA = *(const short8*)&WtA[kb];
      short8 bB = *(const short8*)&WtB[kb];
      acc0 = __builtin_amdgcn_mfma_f32_16x16x32_bf16(a, bA, acc0, 0, 0, 0);
      acc1 = __builtin_amdgcn_mfma_f32_16x16x32_bf16(a, bB, acc1, 0, 0, 0);
    }
    const int colA = n0 + r, colB = n0 + 16 + r;
    const float bA2 = b2[colA], bB2 = b2[colB];
    #pragma unroll
    for (int q = 0; q < 4; ++q) {
      const int row = gt*16 + kg*4 + q;
      out[(size_t)(b0+row)*HID + colA] = acc0[q] + bA2;
      out[(size_t)(b0+row)*HID + colB] = acc1[q] + bB2;
    }
  }
}

extern "C" void kernel_launch(void* const* d_in, const int* in_sizes, int n_in,
                              void* d_out, int out_size, void* d_ws, size_t ws_size,
                              hipStream_t stream) {
  (void)n_in; (void)out_size; (void)ws_size;
  const float* x   = (const float*)d_in[0];
  const int*   ei  = (const int*)  d_in[1];
  const float* W1l = (const float*)d_in[2];
  const float* W1r = (const float*)d_in[3];
  const float* b1  = (const float*)d_in[4];
  const float* W2l = (const float*)d_in[5];
  const float* W2r = (const float*)d_in[6];
  const float* b2  = (const float*)d_in[7];
  float* out = (float*)d_out;
  unsigned char* ws = (unsigned char*)d_ws;

  const int B = in_sizes[0] / (NNODE*3);   // 16384
  prep<<<dim3(129), dim3(256), 0, stream>>>(W2l, W2r, W1l, W1r, ei, ws);
  gnn_fused<<<dim3(B / GB), dim3(BLOCK), 0, stream>>>(x, b1, b2, ws, out);
}